// Round 1
// baseline (204.063 us; speedup 1.0000x reference)
//
#include <hip/hip_runtime.h>

#define NPTS 50000
#define MPTS 50000
#define HN 32
#define KK 15
#define KCD 1024    // 16 (padded K) * 64 (Cin)
#define PSTRIDE 1032
#define FSTRIDE 40

typedef float f32x4 __attribute__((ext_vector_type(4)));
typedef short s16x8 __attribute__((ext_vector_type(8)));

__device__ __forceinline__ unsigned short f2bf(float x) {
    union { float f; unsigned int u; } v; v.f = x;
    unsigned int r = v.u + 0x7fffu + ((v.u >> 16) & 1u);
    return (unsigned short)(r >> 16);
}

// WT[d][kc] = bf16(weights[k][c][d]), kc = k*64+c, zero-padded for k==15
__global__ __launch_bounds__(256) void prep_wt(const float* __restrict__ w,
                                               unsigned short* __restrict__ wt) {
    int t = blockIdx.x * 256 + threadIdx.x;   // t = d*1024 + kc
    if (t >= 64 * KCD) return;
    int d = t >> 10, kc = t & 1023;
    int k = kc >> 6, c = kc & 63;
    float val = (k < KK) ? w[(k * 64 + c) * 64 + d] : 0.f;
    wt[t] = f2bf(val);
}

// signs[n] = (sum_c s_feats[n][c] > 0)
__global__ __launch_bounds__(256) void prep_signs(const float* __restrict__ feats,
                                                  unsigned char* __restrict__ signs) {
    int n = blockIdx.x * 256 + threadIdx.x;
    if (n >= NPTS) return;
    const float4* fp = (const float4*)(feats + (size_t)n * 64);
    float s = 0.f;
    #pragma unroll
    for (int j = 0; j < 16; ++j) { float4 v = fp[j]; s += v.x; s += v.y; s += v.z; s += v.w; }
    signs[n] = (s > 0.f) ? 1 : 0;
}

__global__ __launch_bounds__(256, 2)
void kpconv_main(const float* __restrict__ q_points,
                 const float* __restrict__ s_points,
                 const float* __restrict__ s_feats,
                 const int* __restrict__ ni,
                 const float* __restrict__ kpts,
                 const unsigned short* __restrict__ WT,
                 const unsigned char* __restrict__ signs,
                 float* __restrict__ out) {
    __shared__ unsigned short P_sh[16][PSTRIDE];          // P[m][k*64+c], bf16
    __shared__ unsigned short feats_sh[4][64][FSTRIDE];   // per-wave, [c][h], bf16
    __shared__ unsigned short infl_sh[4][16][FSTRIDE];    // per-wave, [k][h], bf16
    __shared__ float kp_sh[16][3];
    __shared__ float inv_nnum[16];

    int tid = threadIdx.x;
    int w = tid >> 6;
    int lane = tid & 63;
    int m_base = blockIdx.x << 4;

    if (tid < 45) kp_sh[tid / 3][tid % 3] = kpts[tid];
    __syncthreads();

    int h = lane & 31;
    int koff = (lane >> 5) << 3;   // lanes 0-31: k 0..7, lanes 32-63: k 8..15

    // hoist this lane's 8 kernel points into registers; k==15 -> far away => infl 0
    float kpx[8], kpy[8], kpz[8];
    #pragma unroll
    for (int jj = 0; jj < 8; ++jj) {
        int k = koff + jj;
        if (k < KK) { kpx[jj] = kp_sh[k][0]; kpy[jj] = kp_sh[k][1]; kpz[jj] = kp_sh[k][2]; }
        else        { kpx[jj] = 1e9f; kpy[jj] = 1e9f; kpz[jj] = 1e9f; }
    }

    for (int mi = 0; mi < 4; ++mi) {
        int m_l = mi * 4 + w;
        int m = m_base + m_l;
        int idx = ni[m * HN + h];
        bool valid = idx < NPTS;
        float px, py, pz;
        if (valid) {
            const float* sp = s_points + (size_t)idx * 3;
            px = sp[0]; py = sp[1]; pz = sp[2];
        } else { px = py = pz = 1e6f; }
        float qx = q_points[m * 3], qy = q_points[m * 3 + 1], qz = q_points[m * 3 + 2];
        float rx = px - qx, ry = py - qy, rz = pz - qz;

        float maxi = 0.f;
        #pragma unroll
        for (int jj = 0; jj < 8; ++jj) {
            float dx = rx - kpx[jj];
            float dy = ry - kpy[jj];
            float dz = rz - kpz[jj];
            float d2 = dx * dx + dy * dy + dz * dz;
            float infl = 1.f - sqrtf(d2);
            infl = infl > 0.f ? infl : 0.f;
            maxi = fmaxf(maxi, infl);
            infl_sh[w][koff + jj][h] = f2bf(infl);
        }
        maxi = fmaxf(maxi, __shfl_xor(maxi, 32));
        bool alive = valid && (maxi > 0.f);
        unsigned long long aliveMask = __ballot(alive);   // bits h and h+32 identical

        // nnum from precomputed sign table
        bool posflag = false;
        if (lane < 32 && valid) posflag = (signs[idx] != 0);
        unsigned long long pm = __ballot(posflag);
        int cnt = __popcll(pm);
        if (lane == 0) inv_nnum[m_l] = 1.f / (float)(cnt < 1 ? 1 : cnt);

        // gather features (2 lanes per neighbor), skip dead neighbors
        int h2 = lane >> 1, half = lane & 1;
        int idx2 = __shfl(idx, h2, 64);
        bool alive2 = (aliveMask >> h2) & 1;
        if (alive2) {
            const float4* fp = (const float4*)(s_feats + (size_t)idx2 * 64 + half * 32);
            #pragma unroll
            for (int j = 0; j < 8; ++j) {
                float4 v = fp[j];
                int c = half * 32 + j * 4;
                feats_sh[w][c + 0][h2] = f2bf(v.x);
                feats_sh[w][c + 1][h2] = f2bf(v.y);
                feats_sh[w][c + 2][h2] = f2bf(v.z);
                feats_sh[w][c + 3][h2] = f2bf(v.w);
            }
        } else {
            #pragma unroll
            for (int j = 0; j < 8; ++j) {
                int c = half * 32 + j * 4;
                feats_sh[w][c + 0][h2] = 0;
                feats_sh[w][c + 1][h2] = 0;
                feats_sh[w][c + 2][h2] = 0;
                feats_sh[w][c + 3][h2] = 0;
            }
        }

        // step 3: P[m] = infl(16k x 32h) @ feats(32h x 64c) via 4 MFMAs
        int row = lane & 15, kq = (lane >> 4) << 3;
        s16x8 afrag = *(const s16x8*)&infl_sh[w][row][kq];
        #pragma unroll
        for (int ch = 0; ch < 4; ++ch) {
            s16x8 bfrag = *(const s16x8*)&feats_sh[w][ch * 16 + row][kq];
            f32x4 acc = {0.f, 0.f, 0.f, 0.f};
            acc = __builtin_amdgcn_mfma_f32_16x16x32_bf16(afrag, bfrag, acc, 0, 0, 0);
            int cc = ch * 16 + row;
            #pragma unroll
            for (int r = 0; r < 4; ++r) {
                int k2 = ((lane >> 4) << 2) + r;
                P_sh[m_l][k2 * 64 + cc] = f2bf(acc[r]);
            }
        }
    }
    __syncthreads();

    // step 4: out tile (16m x 16d per wave) = P(16m x 1024) @ WT^T, K-loop of 32 MFMAs
    {
        int row = lane & 15, kq = (lane >> 4) << 3;
        int dbase = w << 4;
        f32x4 acc = {0.f, 0.f, 0.f, 0.f};
        const unsigned short* wtp = WT + (size_t)(dbase + row) * KCD + kq;
        #pragma unroll 8
        for (int step = 0; step < 32; ++step) {
            s16x8 a = *(const s16x8*)&P_sh[row][step * 32 + kq];
            s16x8 b = *(const s16x8*)&wtp[step * 32];
            acc = __builtin_amdgcn_mfma_f32_16x16x32_bf16(a, b, acc, 0, 0, 0);
        }
        #pragma unroll
        for (int r = 0; r < 4; ++r) {
            int m_l = ((lane >> 4) << 2) + r;
            out[(size_t)(m_base + m_l) * 64 + dbase + row] = acc[r] * inv_nnum[m_l];
        }
    }
}

extern "C" void kernel_launch(void* const* d_in, const int* in_sizes, int n_in,
                              void* d_out, int out_size, void* d_ws, size_t ws_size,
                              hipStream_t stream) {
    const float* q  = (const float*)d_in[0];
    const float* sp = (const float*)d_in[1];
    const float* sf = (const float*)d_in[2];
    const int*   ni = (const int*)d_in[3];
    const float* kp = (const float*)d_in[4];
    const float* wt = (const float*)d_in[5];
    float* out = (float*)d_out;

    unsigned short* WT = (unsigned short*)d_ws;                      // 64*1024*2 = 128 KB
    unsigned char* signs = (unsigned char*)d_ws + 64 * KCD * 2;      // + 50000 B

    hipLaunchKernelGGL(prep_wt, dim3(64 * KCD / 256), dim3(256), 0, stream, wt, WT);
    hipLaunchKernelGGL(prep_signs, dim3((NPTS + 255) / 256), dim3(256), 0, stream, sf, signs);
    hipLaunchKernelGGL(kpconv_main, dim3(MPTS / 16), dim3(256), 0, stream,
                       q, sp, sf, ni, kp, WT, signs, out);
}

// Round 2
// 166.462 us; speedup vs baseline: 1.2259x; 1.2259x over previous
//
#include <hip/hip_runtime.h>

#define NPTS 50000
#define MPTS 50000
#define HN 32
#define KCD 960      // 15 kernel pts * 64 Cin
#define PSTRIDE 968  // +8 pad: row stride 1936B -> 4-bank offset per row, 2-way max
#define FSTRIDE 40   // 32 + 8: mult-of-8 for b128 alignment, 20-dword row stride

typedef float f32x4 __attribute__((ext_vector_type(4)));
typedef short s16x8 __attribute__((ext_vector_type(8)));

__device__ __forceinline__ unsigned short bf_rne(float x) {
    union { float f; unsigned u; } v; v.f = x;
    unsigned r = v.u + 0x7fffu + ((v.u >> 16) & 1u);
    return (unsigned short)(r >> 16);
}
__device__ __forceinline__ unsigned short bf_trunc(float x) {
    union { float f; unsigned u; } v; v.f = x;
    return (unsigned short)(v.u >> 16);   // compiles to d16_hi store, 0 VALU
}

// blocks [0,240): WT[d][kc] = bf16(weights[k][c][d]); blocks [240,436): sign table
__global__ __launch_bounds__(256) void prep(const float* __restrict__ w,
                                            const float* __restrict__ feats,
                                            unsigned short* __restrict__ WT,
                                            unsigned char* __restrict__ signs) {
    int b = blockIdx.x;
    if (b < 240) {
        int t = b * 256 + threadIdx.x;        // t = d*960 + kc, exactly 61440 threads
        int d = t / 960, kc = t - d * 960;
        int k = kc >> 6, c = kc & 63;
        WT[t] = bf_rne(w[(k * 64 + c) * 64 + d]);
    } else {
        int n = (b - 240) * 256 + threadIdx.x;
        if (n < NPTS) {
            const float4* fp = (const float4*)(feats + (size_t)n * 64);
            float s = 0.f;
            #pragma unroll
            for (int j = 0; j < 16; ++j) { float4 v = fp[j]; s += v.x + v.y + v.z + v.w; }
            signs[n] = (s > 0.f) ? 1 : 0;
        }
    }
}

__global__ __launch_bounds__(256, 3)
void kpconv_main(const float* __restrict__ q_points,
                 const float* __restrict__ s_points,
                 const float* __restrict__ s_feats,
                 const int* __restrict__ ni,
                 const float* __restrict__ kpts,
                 const unsigned short* __restrict__ WT,
                 const unsigned char* __restrict__ signs,
                 float* __restrict__ out) {
    __shared__ __align__(16) unsigned short P_sh[16][PSTRIDE];       // 30976 B
    __shared__ __align__(16) unsigned short feats_sh[4][64][FSTRIDE]; // 20480 B
    __shared__ __align__(16) float rpos_sh[4][3][32];                 // 1536 B
    __shared__ float kp_sh[16][3];
    __shared__ float q_sh[16][3];
    __shared__ float inv_nnum[16];
    // total ~53.4 KB -> 3 blocks/CU

    int tid = threadIdx.x, w = tid >> 6, lane = tid & 63;
    int m_base = blockIdx.x << 4;

    if (tid < 48) {
        kp_sh[tid / 3][tid % 3] = (tid < 45) ? kpts[tid] : 1e9f;  // row 15 = phantom
        q_sh[tid / 3][tid % 3] = q_points[m_base * 3 + tid];
    }
    __syncthreads();

    int h = lane & 31;
    int row = lane & 15, quad = lane >> 4, kq = quad << 3;

    // this lane's A-frag kernel point (k = row; row 15 far away -> infl 0)
    float kx = kp_sh[row][0], ky = kp_sh[row][1], kz = kp_sh[row][2];

    // conservative alive radius: ||r|| >= 1+max||kp|| implies all influences 0
    float maxn2 = 0.f;
    #pragma unroll
    for (int k = 0; k < 15; ++k) {
        float a = kp_sh[k][0], b = kp_sh[k][1], c = kp_sh[k][2];
        maxn2 = fmaxf(maxn2, a * a + b * b + c * c);
    }
    float R0 = 1.f + sqrtf(maxn2);
    float R0sq = R0 * R0;

    // prefetch idx/pos/sign for all 4 sub-iterations: 4 independent chains in flight
    int idx4[4]; float ppx[4], ppy[4], ppz[4]; unsigned char sg4[4];
    #pragma unroll
    for (int mi = 0; mi < 4; ++mi)
        idx4[mi] = ni[(m_base + mi * 4 + w) * HN + h];
    #pragma unroll
    for (int mi = 0; mi < 4; ++mi) {
        bool valid = idx4[mi] < NPTS;
        const float* sp = s_points + (size_t)(valid ? idx4[mi] : 0) * 3;
        float px = sp[0], py = sp[1], pz = sp[2];
        unsigned char sg = signs[valid ? idx4[mi] : 0];
        ppx[mi] = valid ? px : 1e6f;
        ppy[mi] = valid ? py : 1e6f;
        ppz[mi] = valid ? pz : 1e6f;
        sg4[mi] = valid ? sg : 0;
    }

    #pragma unroll
    for (int mi = 0; mi < 4; ++mi) {
        int m_l = mi * 4 + w;
        float rx = ppx[mi] - q_sh[m_l][0];
        float ry = ppy[mi] - q_sh[m_l][1];
        float rz = ppz[mi] - q_sh[m_l][2];
        if (lane < 32) {
            rpos_sh[w][0][h] = rx; rpos_sh[w][1][h] = ry; rpos_sh[w][2][h] = rz;
        }

        // nnum from sign table
        unsigned long long pm = __ballot((lane < 32) && (idx4[mi] < NPTS) && sg4[mi]);
        if (lane == 0) {
            int cnt = __popcll(pm);
            inv_nnum[m_l] = 1.f / (float)(cnt < 1 ? 1 : cnt);
        }

        // gather decision (2 lanes per neighbor), radius test: superset of alive
        int h2 = lane >> 1, half = lane & 1;
        float rx2 = __shfl(rx, h2), ry2 = __shfl(ry, h2), rz2 = __shfl(rz, h2);
        int idx2 = __shfl(idx4[mi], h2);
        bool alive2 = (idx2 < NPTS) && (rx2 * rx2 + ry2 * ry2 + rz2 * rz2 < R0sq);

        float4 fv[8];
        #pragma unroll
        for (int j = 0; j < 8; ++j) fv[j] = float4{0.f, 0.f, 0.f, 0.f};
        if (alive2) {
            const float4* fp = (const float4*)(s_feats + (size_t)idx2 * 64 + half * 32);
            #pragma unroll
            for (int j = 0; j < 8; ++j) { int jj = (j + half) & 7; fv[j] = fp[jj]; }
        }

        // influence in A-frag order (k = row, h = kq+j), overlaps the gather latency
        float4 ra0 = *(const float4*)&rpos_sh[w][0][kq];
        float4 ra1 = *(const float4*)&rpos_sh[w][0][kq + 4];
        float4 rb0 = *(const float4*)&rpos_sh[w][1][kq];
        float4 rb1 = *(const float4*)&rpos_sh[w][1][kq + 4];
        float4 rc0 = *(const float4*)&rpos_sh[w][2][kq];
        float4 rc1 = *(const float4*)&rpos_sh[w][2][kq + 4];
        float hx[8] = {ra0.x, ra0.y, ra0.z, ra0.w, ra1.x, ra1.y, ra1.z, ra1.w};
        float hy[8] = {rb0.x, rb0.y, rb0.z, rb0.w, rb1.x, rb1.y, rb1.z, rb1.w};
        float hz[8] = {rc0.x, rc0.y, rc0.z, rc0.w, rc1.x, rc1.y, rc1.z, rc1.w};
        s16x8 afrag;
        #pragma unroll
        for (int j = 0; j < 8; ++j) {
            float dx = hx[j] - kx, dy = hy[j] - ky, dz = hz[j] - kz;
            float d2 = dx * dx + dy * dy + dz * dz;
            float infl = 1.f - sqrtf(d2);
            infl = infl > 0.f ? infl : 0.f;
            afrag[j] = (short)bf_trunc(infl);
        }

        // feats -> LDS [c][h], half-offset write order keeps halves in disjoint banks
        #pragma unroll
        for (int j = 0; j < 8; ++j) {
            int jj = (j + half) & 7;
            int c = half * 32 + jj * 4;
            float4 v = fv[j];
            feats_sh[w][c + 0][h2] = bf_trunc(v.x);
            feats_sh[w][c + 1][h2] = bf_trunc(v.y);
            feats_sh[w][c + 2][h2] = bf_trunc(v.z);
            feats_sh[w][c + 3][h2] = bf_trunc(v.w);
        }

        // P[m_l] = infl(16k x 32h) @ feats(32h x 64c), quad-XOR swizzled store
        #pragma unroll
        for (int ch = 0; ch < 4; ++ch) {
            s16x8 bfrag = *(const s16x8*)&feats_sh[w][ch * 16 + row][kq];
            f32x4 acc = {0.f, 0.f, 0.f, 0.f};
            acc = __builtin_amdgcn_mfma_f32_16x16x32_bf16(afrag, bfrag, acc, 0, 0, 0);
            int cc = ch * 16 + row;
            #pragma unroll
            for (int r = 0; r < 4; ++r) {
                int k2 = quad * 4 + r;
                if (k2 < 15) {
                    int col = (k2 << 6) | (cc ^ ((k2 >> 2) << 4));
                    P_sh[m_l][col] = bf_trunc(acc[r]);
                }
            }
        }
    }
    __syncthreads();

    // out tile (16m x 16d per wave) = P(16m x 960) @ WT^T, 30 MFMAs
    {
        int dbase = w << 4;
        f32x4 acc = {0.f, 0.f, 0.f, 0.f};
        const unsigned short* wtp = WT + (size_t)(dbase + row) * KCD + kq;
        #pragma unroll 6
        for (int s = 0; s < 30; ++s) {
            int k = s >> 1;
            int c0 = ((s & 1) << 5) + kq;
            int cx = c0 ^ (((k >> 2) & 3) << 4);
            s16x8 a = *(const s16x8*)&P_sh[row][(k << 6) | cx];
            s16x8 b = *(const s16x8*)&wtp[s * 32];
            acc = __builtin_amdgcn_mfma_f32_16x16x32_bf16(a, b, acc, 0, 0, 0);
        }
        #pragma unroll
        for (int r = 0; r < 4; ++r) {
            int m_l = quad * 4 + r;
            out[(size_t)(m_base + m_l) * 64 + dbase + row] = acc[r] * inv_nnum[m_l];
        }
    }
}

extern "C" void kernel_launch(void* const* d_in, const int* in_sizes, int n_in,
                              void* d_out, int out_size, void* d_ws, size_t ws_size,
                              hipStream_t stream) {
    const float* q  = (const float*)d_in[0];
    const float* sp = (const float*)d_in[1];
    const float* sf = (const float*)d_in[2];
    const int*   ni = (const int*)d_in[3];
    const float* kp = (const float*)d_in[4];
    const float* wt = (const float*)d_in[5];
    float* out = (float*)d_out;

    unsigned short* WT = (unsigned short*)d_ws;                     // 64*960*2 = 122880 B
    unsigned char* signs = (unsigned char*)d_ws + 64 * KCD * 2;     // + 50000 B

    hipLaunchKernelGGL(prep, dim3(240 + (NPTS + 255) / 256), dim3(256), 0, stream,
                       wt, sf, WT, signs);
    hipLaunchKernelGGL(kpconv_main, dim3(MPTS / 16), dim3(256), 0, stream,
                       q, sp, sf, ni, kp, WT, signs, out);
}

// Round 5
// 164.182 us; speedup vs baseline: 1.2429x; 1.0139x over previous
//
#include <hip/hip_runtime.h>

#define NPTS 50000
#define MPTS 50000
#define HN 32
#define KCD 960      // 15 kernel pts * 64 Cin
#define PSTRIDE 968  // +8 pad
#define FSTRIDE 40   // 32 + 8: b128-aligned rows

typedef float f32x4 __attribute__((ext_vector_type(4)));
typedef short s16x8 __attribute__((ext_vector_type(8)));

__device__ __forceinline__ unsigned short bf_rne(float x) {
    union { float f; unsigned u; } v; v.f = x;
    unsigned r = v.u + 0x7fffu + ((v.u >> 16) & 1u);
    return (unsigned short)(r >> 16);
}
__device__ __forceinline__ unsigned short bf_trunc(float x) {
    union { float f; unsigned u; } v; v.f = x;
    return (unsigned short)(v.u >> 16);
}

// blocks [0,240): WT[d][kc]=bf16(w[k][c][d]) via coalesced read / scattered write
// blocks [240,3365): signs, 16 rows/block, 16 lanes/row, coalesced float4 reads
__global__ __launch_bounds__(256) void prep(const float* __restrict__ w,
                                            const float* __restrict__ feats,
                                            unsigned short* __restrict__ WT,
                                            unsigned char* __restrict__ signs) {
    int b = blockIdx.x;
    if (b < 240) {
        int t = b * 256 + threadIdx.x;     // t = (k*64+c)*64 + d, 61440 threads
        int kc = t >> 6, d = t & 63;
        WT[d * KCD + kc] = bf_rne(w[t]);   // read coalesced; 120KB scatter write
    } else {
        int lane = threadIdx.x & 63, wv = threadIdx.x >> 6;
        int r4 = lane >> 4, c16 = lane & 15;
        int n = (b - 240) * 16 + wv * 4 + r4;      // 3125*16 = 50000 exactly
        float4 v = *(const float4*)(feats + (size_t)n * 64 + c16 * 4);
        float s = v.x + v.y + v.z + v.w;
        s += __shfl_xor(s, 1); s += __shfl_xor(s, 2);
        s += __shfl_xor(s, 4); s += __shfl_xor(s, 8);
        if (c16 == 0) signs[n] = (s > 0.f) ? 1 : 0;
    }
}

__global__ __launch_bounds__(256, 3)
void kpconv_main(const float* __restrict__ q_points,
                 const float* __restrict__ s_points,
                 const float* __restrict__ s_feats,
                 const int* __restrict__ ni,
                 const float* __restrict__ kpts,
                 const unsigned short* __restrict__ WT,
                 const unsigned char* __restrict__ signs,
                 float* __restrict__ out) {
    __shared__ __align__(16) unsigned short P_sh[16][PSTRIDE];        // 30976 B
    __shared__ __align__(16) unsigned short feats_sh[4][64][FSTRIDE]; // 20480 B
    __shared__ __align__(16) float rpos_sh[4][3][32];                 // 1536 B
    __shared__ float kp_sh[16][3];
    __shared__ float q_sh[16][3];
    __shared__ float inv_nnum[16];
    // ~53.4 KB -> 3 blocks/CU

    int tid = threadIdx.x, w = tid >> 6, lane = tid & 63;
    int m_base = blockIdx.x << 4;

    if (tid < 48) {
        kp_sh[tid / 3][tid % 3] = (tid < 45) ? kpts[tid] : 1e9f;  // row 15 phantom
        q_sh[tid / 3][tid % 3] = q_points[m_base * 3 + tid];
    }
    __syncthreads();

    int h = lane & 31;
    int row = lane & 15, quad = lane >> 4, kq = quad << 3;
    int h2 = lane >> 1, half = lane & 1;

    // A-frag kernel point for this lane (k = row)
    float kx = kp_sh[row][0], ky = kp_sh[row][1], kz = kp_sh[row][2];

    // pair-test kernel points: half 0 -> k0..7, half 1 -> k8..15 (15 = phantom)
    float tkx[8], tky[8], tkz[8];
    #pragma unroll
    for (int j = 0; j < 8; ++j) {
        int k = half * 8 + j;
        tkx[j] = kp_sh[k][0]; tky[j] = kp_sh[k][1]; tkz[j] = kp_sh[k][2];
    }

    // prefetch idx/pos/sign for all 4 sub-iterations
    int idx4[4]; float rxa[4], rya[4], rza[4]; unsigned char sg4[4];
    #pragma unroll
    for (int mi = 0; mi < 4; ++mi)
        idx4[mi] = ni[(m_base + mi * 4 + w) * HN + h];
    #pragma unroll
    for (int mi = 0; mi < 4; ++mi) {
        int m_l = mi * 4 + w;
        bool valid = idx4[mi] < NPTS;
        const float* sp = s_points + (size_t)(valid ? idx4[mi] : 0) * 3;
        float px = sp[0], py = sp[1], pz = sp[2];
        unsigned char sg = signs[valid ? idx4[mi] : 0];
        rxa[mi] = (valid ? px : 1e6f) - q_sh[m_l][0];
        rya[mi] = (valid ? py : 1e6f) - q_sh[m_l][1];
        rza[mi] = (valid ? pz : 1e6f) - q_sh[m_l][2];
        sg4[mi] = valid ? sg : 0;
    }

    // exact alive test for all mi upfront: exists k with dist^2 < 1.
    // Branch-free OR + UNCONDITIONAL shfl (a short-circuit || here let the
    // compiler fold the bpermute source under divergence -> garbage reads).
    bool alive2[4]; int idx2c[4];
    #pragma unroll
    for (int mi = 0; mi < 4; ++mi) {
        float rx2 = __shfl(rxa[mi], h2);
        float ry2 = __shfl(rya[mi], h2);
        float rz2 = __shfl(rza[mi], h2);
        int idx2 = __shfl(idx4[mi], h2);
        int av = 0;
        #pragma unroll
        for (int j = 0; j < 8; ++j) {
            float dx = rx2 - tkx[j], dy = ry2 - tky[j], dz = rz2 - tkz[j];
            float d2 = dx * dx + dy * dy + dz * dz;
            av |= (d2 < 1.f) ? 1 : 0;
        }
        av |= __shfl_xor(av, 1);           // executed by all lanes, no divergence
        alive2[mi] = (idx2 < NPTS) && (av != 0);
        idx2c[mi] = idx2 < NPTS ? idx2 : 0;
    }

    // double-buffered pipelined gather
    float4 fv[2][8];
    #define ISSUE(buf, mi)                                                        \
        {                                                                         \
            _Pragma("unroll")                                                     \
            for (int j = 0; j < 8; ++j) fv[buf][j] = float4{0.f, 0.f, 0.f, 0.f};  \
            if (alive2[mi]) {                                                     \
                const float4* fp =                                                \
                    (const float4*)(s_feats + (size_t)idx2c[mi] * 64 + half * 32);\
                _Pragma("unroll")                                                 \
                for (int j = 0; j < 8; ++j) {                                     \
                    int jj = (j + half) & 7;                                      \
                    fv[buf][j] = fp[jj];                                          \
                }                                                                 \
            }                                                                     \
        }

    ISSUE(0, 0)

    #pragma unroll
    for (int mi = 0; mi < 4; ++mi) {
        int cur = mi & 1;
        if (mi < 3) { ISSUE(1 - cur, mi + 1) }

        int m_l = mi * 4 + w;
        if (lane < 32) {
            rpos_sh[w][0][h] = rxa[mi];
            rpos_sh[w][1][h] = rya[mi];
            rpos_sh[w][2][h] = rza[mi];
        }

        unsigned long long pm = __ballot((lane < 32) && (idx4[mi] < NPTS) && sg4[mi]);
        if (lane == 0) {
            int cnt = __popcll(pm);
            inv_nnum[m_l] = 1.f / (float)(cnt < 1 ? 1 : cnt);
        }

        // influence in A-frag order (k = row, h = kq+j)
        float4 ra0 = *(const float4*)&rpos_sh[w][0][kq];
        float4 ra1 = *(const float4*)&rpos_sh[w][0][kq + 4];
        float4 rb0 = *(const float4*)&rpos_sh[w][1][kq];
        float4 rb1 = *(const float4*)&rpos_sh[w][1][kq + 4];
        float4 rc0 = *(const float4*)&rpos_sh[w][2][kq];
        float4 rc1 = *(const float4*)&rpos_sh[w][2][kq + 4];
        float hx[8] = {ra0.x, ra0.y, ra0.z, ra0.w, ra1.x, ra1.y, ra1.z, ra1.w};
        float hy[8] = {rb0.x, rb0.y, rb0.z, rb0.w, rb1.x, rb1.y, rb1.z, rb1.w};
        float hz[8] = {rc0.x, rc0.y, rc0.z, rc0.w, rc1.x, rc1.y, rc1.z, rc1.w};
        s16x8 afrag;
        #pragma unroll
        for (int j = 0; j < 8; ++j) {
            float dx = hx[j] - kx, dy = hy[j] - ky, dz = hz[j] - kz;
            float d2 = dx * dx + dy * dy + dz * dz;
            float infl = 1.f - sqrtf(d2);
            infl = infl > 0.f ? infl : 0.f;
            afrag[j] = (short)bf_trunc(infl);
        }

        // feats -> LDS [c][h2], half-rotated write order
        #pragma unroll
        for (int j = 0; j < 8; ++j) {
            int jj = (j + half) & 7;
            int c = half * 32 + jj * 4;
            float4 v = fv[cur][j];
            feats_sh[w][c + 0][h2] = bf_trunc(v.x);
            feats_sh[w][c + 1][h2] = bf_trunc(v.y);
            feats_sh[w][c + 2][h2] = bf_trunc(v.z);
            feats_sh[w][c + 3][h2] = bf_trunc(v.w);
        }

        // P[m_l] = infl(16k x 32h) @ feats(32h x 64c), quad-XOR swizzled store
        #pragma unroll
        for (int ch = 0; ch < 4; ++ch) {
            s16x8 bfrag = *(const s16x8*)&feats_sh[w][ch * 16 + row][kq];
            f32x4 acc = {0.f, 0.f, 0.f, 0.f};
            acc = __builtin_amdgcn_mfma_f32_16x16x32_bf16(afrag, bfrag, acc, 0, 0, 0);
            int cc = ch * 16 + row;
            #pragma unroll
            for (int r = 0; r < 4; ++r) {
                int k2 = quad * 4 + r;
                if (k2 < 15) {
                    int col = (k2 << 6) | (cc ^ ((k2 >> 2) << 4));
                    P_sh[m_l][col] = bf_trunc(acc[r]);
                }
            }
        }
    }
    __syncthreads();

    // out tile (16m x 16d per wave) = P(16m x 960) @ WT^T, 30 MFMAs
    {
        int dbase = w << 4;
        f32x4 acc = {0.f, 0.f, 0.f, 0.f};
        const unsigned short* wtp = WT + (size_t)(dbase + row) * KCD + kq;
        #pragma unroll 6
        for (int s = 0; s < 30; ++s) {
            int k = s >> 1;
            int c0 = ((s & 1) << 5) + kq;
            int cx = c0 ^ (((k >> 2) & 3) << 4);
            s16x8 a = *(const s16x8*)&P_sh[row][(k << 6) | cx];
            s16x8 b = *(const s16x8*)&wtp[s * 32];
            acc = __builtin_amdgcn_mfma_f32_16x16x32_bf16(a, b, acc, 0, 0, 0);
        }
        #pragma unroll
        for (int r = 0; r < 4; ++r) {
            int m_l = quad * 4 + r;
            out[(size_t)(m_base + m_l) * 64 + dbase + row] = acc[r] * inv_nnum[m_l];
        }
    }
}

extern "C" void kernel_launch(void* const* d_in, const int* in_sizes, int n_in,
                              void* d_out, int out_size, void* d_ws, size_t ws_size,
                              hipStream_t stream) {
    const float* q  = (const float*)d_in[0];
    const float* sp = (const float*)d_in[1];
    const float* sf = (const float*)d_in[2];
    const int*   ni = (const int*)d_in[3];
    const float* kp = (const float*)d_in[4];
    const float* wt = (const float*)d_in[5];
    float* out = (float*)d_out;

    unsigned short* WT = (unsigned short*)d_ws;                  // 64*960*2 = 122880 B
    unsigned char* signs = (unsigned char*)d_ws + 64 * KCD * 2;  // + 50000 B

    hipLaunchKernelGGL(prep, dim3(240 + NPTS / 16), dim3(256), 0, stream,
                       wt, sf, WT, signs);
    hipLaunchKernelGGL(kpconv_main, dim3(MPTS / 16), dim3(256), 0, stream,
                       q, sp, sf, ni, kp, WT, signs, out);
}

// Round 6
// 152.938 us; speedup vs baseline: 1.3343x; 1.0735x over previous
//
#include <hip/hip_runtime.h>

#define NPTS 50000
#define MPTS 50000
#define HN 32
#define KCD 960      // 15 kernel pts * 64 Cin
#define PSTRIDE 968  // +8 pad

typedef float f32x4 __attribute__((ext_vector_type(4)));
typedef short s16x8 __attribute__((ext_vector_type(8)));

__device__ __forceinline__ unsigned short bf_rne(float x) {
    union { float f; unsigned u; } v; v.f = x;
    unsigned r = v.u + 0x7fffu + ((v.u >> 16) & 1u);
    return (unsigned short)(r >> 16);
}
__device__ __forceinline__ unsigned short bf_trunc(float x) {
    union { float f; unsigned u; } v; v.f = x;
    return (unsigned short)(v.u >> 16);
}
// pack two floats' bf16-truncations into one dword: low16=bf(lo), high16=bf(hi)
__device__ __forceinline__ unsigned pack_bf(float lo, float hi) {
    union { float f; unsigned u; } a, b; a.f = lo; b.f = hi;
    return __builtin_amdgcn_perm(b.u, a.u, 0x07060302u);
}

// blocks [0,240): WT[d][kc]=bf16(w[k][c][d]) coalesced read / scattered write
// blocks [240,3365): signs, 16 rows/block, 16 lanes/row, coalesced float4 reads
__global__ __launch_bounds__(256) void prep(const float* __restrict__ w,
                                            const float* __restrict__ feats,
                                            unsigned short* __restrict__ WT,
                                            unsigned char* __restrict__ signs) {
    int b = blockIdx.x;
    if (b < 240) {
        int t = b * 256 + threadIdx.x;     // t = (k*64+c)*64 + d
        int kc = t >> 6, d = t & 63;
        WT[d * KCD + kc] = bf_rne(w[t]);
    } else {
        int lane = threadIdx.x & 63, wv = threadIdx.x >> 6;
        int r4 = lane >> 4, c16 = lane & 15;
        int n = (b - 240) * 16 + wv * 4 + r4;      // 3125*16 = 50000 exactly
        float4 v = *(const float4*)(feats + (size_t)n * 64 + c16 * 4);
        float s = v.x + v.y + v.z + v.w;
        s += __shfl_xor(s, 1); s += __shfl_xor(s, 2);
        s += __shfl_xor(s, 4); s += __shfl_xor(s, 8);
        if (c16 == 0) signs[n] = (s > 0.f) ? 1 : 0;
    }
}

__global__ __launch_bounds__(256, 4)
void kpconv_main(const float* __restrict__ q_points,
                 const float* __restrict__ s_points,
                 const float* __restrict__ s_feats,
                 const int* __restrict__ ni,
                 const float* __restrict__ kpts,
                 const unsigned short* __restrict__ WT,
                 const unsigned char* __restrict__ signs,
                 float* __restrict__ out) {
    __shared__ __align__(16) unsigned short P_sh[16][PSTRIDE];  // 30976 B
    __shared__ __align__(16) float rpos_sh[4][3][32];           // 1536 B
    __shared__ int ni_sh[4][4][32];                             // 2048 B; alive?idx:NPTS
    __shared__ float kp_sh[16][3];
    __shared__ float q_sh[16][3];
    __shared__ float inv_nnum[16];
    // ~35 KB -> 4 blocks/CU

    int tid = threadIdx.x, w = tid >> 6, lane = tid & 63;
    int m_base = blockIdx.x << 4;

    if (tid < 48) {
        kp_sh[tid / 3][tid % 3] = (tid < 45) ? kpts[tid] : 1e9f;  // row 15 phantom
        q_sh[tid / 3][tid % 3] = q_points[m_base * 3 + tid];
    }
    __syncthreads();

    int h = lane & 31;
    int row = lane & 15, quad = lane >> 4, kq = quad << 3;
    int h2 = lane >> 1, half = lane & 1;

    // A-frag kernel point for this lane (k = row)
    float kx = kp_sh[row][0], ky = kp_sh[row][1], kz = kp_sh[row][2];

    // pair-test kernel points: half 0 -> k0..7, half 1 -> k8..15 (15 = phantom)
    float tkx[8], tky[8], tkz[8];
    #pragma unroll
    for (int j = 0; j < 8; ++j) {
        int k = half * 8 + j;
        tkx[j] = kp_sh[k][0]; tky[j] = kp_sh[k][1]; tkz[j] = kp_sh[k][2];
    }

    // prefetch idx/pos/sign for all 4 sub-iterations
    int idx4[4]; float rxa[4], rya[4], rza[4]; unsigned char sg4[4];
    #pragma unroll
    for (int mi = 0; mi < 4; ++mi)
        idx4[mi] = ni[(m_base + mi * 4 + w) * HN + h];
    #pragma unroll
    for (int mi = 0; mi < 4; ++mi) {
        int m_l = mi * 4 + w;
        bool valid = idx4[mi] < NPTS;
        const float* sp = s_points + (size_t)(valid ? idx4[mi] : 0) * 3;
        float px = sp[0], py = sp[1], pz = sp[2];
        unsigned char sg = signs[valid ? idx4[mi] : 0];
        rxa[mi] = (valid ? px : 1e6f) - q_sh[m_l][0];
        rya[mi] = (valid ? py : 1e6f) - q_sh[m_l][1];
        rza[mi] = (valid ? pz : 1e6f) - q_sh[m_l][2];
        sg4[mi] = valid ? sg : 0;
    }

    // upfront: exact alive test -> ni_sh sentinel, and nnum
    #pragma unroll
    for (int mi = 0; mi < 4; ++mi) {
        float rx2 = __shfl(rxa[mi], h2);
        float ry2 = __shfl(rya[mi], h2);
        float rz2 = __shfl(rza[mi], h2);
        int idx2 = __shfl(idx4[mi], h2);
        int av = 0;
        #pragma unroll
        for (int j = 0; j < 8; ++j) {
            float dx = rx2 - tkx[j], dy = ry2 - tky[j], dz = rz2 - tkz[j];
            float d2 = dx * dx + dy * dy + dz * dz;
            av |= (d2 < 1.f) ? 1 : 0;
        }
        av |= __shfl_xor(av, 1);           // unconditional: no divergence
        bool alive = (idx2 < NPTS) && (av != 0);
        if (half == 0) ni_sh[w][mi][h2] = alive ? idx2 : NPTS;  // even lanes: h2=0..31

        unsigned long long pm = __ballot((lane < 32) && (idx4[mi] < NPTS) && sg4[mi]);
        if (lane == 0) {
            int cnt = __popcll(pm);
            inv_nnum[mi * 4 + w] = 1.f / (float)(cnt < 1 ? 1 : cnt);
        }
    }

    #pragma unroll
    for (int mi = 0; mi < 4; ++mi) {
        int m_l = mi * 4 + w;
        if (lane < 32) {
            rpos_sh[w][0][h] = rxa[mi];
            rpos_sh[w][1][h] = rya[mi];
            rpos_sh[w][2][h] = rza[mi];
        }

        // direct B-frag gather: lane needs feats[idx(kq+j)][ch*16+row], ch=0..3.
        // 16 lanes/quad read 64B contiguous; dead neighbors (sentinel) skipped.
        float g0[8], g1[8], g2[8], g3[8];
        #pragma unroll
        for (int j = 0; j < 8; ++j) {
            int idxj = ni_sh[w][mi][kq + j];
            g0[j] = 0.f; g1[j] = 0.f; g2[j] = 0.f; g3[j] = 0.f;
            if (idxj < NPTS) {
                const float* fp = s_feats + (size_t)idxj * 64 + row;
                g0[j] = fp[0]; g1[j] = fp[16]; g2[j] = fp[32]; g3[j] = fp[48];
            }
        }

        // influence in A-frag order (k = row, h = kq+j), overlaps gather latency
        float4 ra0 = *(const float4*)&rpos_sh[w][0][kq];
        float4 ra1 = *(const float4*)&rpos_sh[w][0][kq + 4];
        float4 rb0 = *(const float4*)&rpos_sh[w][1][kq];
        float4 rb1 = *(const float4*)&rpos_sh[w][1][kq + 4];
        float4 rc0 = *(const float4*)&rpos_sh[w][2][kq];
        float4 rc1 = *(const float4*)&rpos_sh[w][2][kq + 4];
        float hx[8] = {ra0.x, ra0.y, ra0.z, ra0.w, ra1.x, ra1.y, ra1.z, ra1.w};
        float hy[8] = {rb0.x, rb0.y, rb0.z, rb0.w, rb1.x, rb1.y, rb1.z, rb1.w};
        float hz[8] = {rc0.x, rc0.y, rc0.z, rc0.w, rc1.x, rc1.y, rc1.z, rc1.w};
        float infl[8];
        #pragma unroll
        for (int j = 0; j < 8; ++j) {
            float dx = hx[j] - kx, dy = hy[j] - ky, dz = hz[j] - kz;
            float d2 = dx * dx + dy * dy + dz * dz;
            float f = 1.f - sqrtf(d2);
            infl[j] = f > 0.f ? f : 0.f;
        }
        union { unsigned u[4]; s16x8 v; } af;
        #pragma unroll
        for (int p = 0; p < 4; ++p) af.u[p] = pack_bf(infl[2 * p], infl[2 * p + 1]);

        // 4 MFMAs: P[m_l] = infl(16k x 32h) @ feats(32h x 64c)
        #pragma unroll
        for (int ch = 0; ch < 4; ++ch) {
            const float* gs = (ch == 0) ? g0 : (ch == 1) ? g1 : (ch == 2) ? g2 : g3;
            union { unsigned u[4]; s16x8 v; } bf;
            #pragma unroll
            for (int p = 0; p < 4; ++p) bf.u[p] = pack_bf(gs[2 * p], gs[2 * p + 1]);
            f32x4 acc = {0.f, 0.f, 0.f, 0.f};
            acc = __builtin_amdgcn_mfma_f32_16x16x32_bf16(af.v, bf.v, acc, 0, 0, 0);
            int cc = ch * 16 + row;
            #pragma unroll
            for (int r = 0; r < 4; ++r) {
                int k2 = quad * 4 + r;
                if (k2 < 15) {
                    int col = (k2 << 6) | (cc ^ ((k2 >> 2) << 4));
                    P_sh[m_l][col] = bf_trunc(acc[r]);
                }
            }
        }
    }
    __syncthreads();

    // out tile (16m x 16d per wave) = P(16m x 960) @ WT^T, 30 MFMAs
    {
        int dbase = w << 4;
        f32x4 acc = {0.f, 0.f, 0.f, 0.f};
        const unsigned short* wtp = WT + (size_t)(dbase + row) * KCD + kq;
        #pragma unroll 6
        for (int s = 0; s < 30; ++s) {
            int k = s >> 1;
            int c0 = ((s & 1) << 5) + kq;
            int cx = c0 ^ (((k >> 2) & 3) << 4);
            s16x8 a = *(const s16x8*)&P_sh[row][(k << 6) | cx];
            s16x8 b = *(const s16x8*)&wtp[s * 32];
            acc = __builtin_amdgcn_mfma_f32_16x16x32_bf16(a, b, acc, 0, 0, 0);
        }
        #pragma unroll
        for (int r = 0; r < 4; ++r) {
            int m_l = quad * 4 + r;
            out[(size_t)(m_base + m_l) * 64 + dbase + row] = acc[r] * inv_nnum[m_l];
        }
    }
}

extern "C" void kernel_launch(void* const* d_in, const int* in_sizes, int n_in,
                              void* d_out, int out_size, void* d_ws, size_t ws_size,
                              hipStream_t stream) {
    const float* q  = (const float*)d_in[0];
    const float* sp = (const float*)d_in[1];
    const float* sf = (const float*)d_in[2];
    const int*   ni = (const int*)d_in[3];
    const float* kp = (const float*)d_in[4];
    const float* wt = (const float*)d_in[5];
    float* out = (float*)d_out;

    unsigned short* WT = (unsigned short*)d_ws;                  // 64*960*2 = 122880 B
    unsigned char* signs = (unsigned char*)d_ws + 64 * KCD * 2;  // + 50000 B

    hipLaunchKernelGGL(prep, dim3(240 + NPTS / 16), dim3(256), 0, stream,
                       wt, sf, WT, signs);
    hipLaunchKernelGGL(kpconv_main, dim3(MPTS / 16), dim3(256), 0, stream,
                       q, sp, sf, ni, kp, WT, signs, out);
}